// Round 21
// baseline (83.881 us; speedup 1.0000x reference)
//
#include <hip/hip_runtime.h>
#include <math.h>

#define TPB 64

typedef _Float16 half8 __attribute__((ext_vector_type(8)));
typedef _Float16 h2 __attribute__((ext_vector_type(2)));
typedef float f32x4 __attribute__((ext_vector_type(4)));

// ---- XOR swizzle for the [64][64] f16 act tile (row = 128B = 32 banks).
// Verified: SQ_LDS_BANK_CONFLICT 1.285e7 -> 0 (round 4).
__device__ __forceinline__ int swz(int row, int col) {
    return row * 64 + ((((col >> 3) ^ row) & 7) << 3) + (col & 7);
}

// pack two f32 -> one u32 of 2 f16 (RTZ; exact for the small ints we pack).
__device__ __forceinline__ unsigned int pk_f16(float a, float b) {
    auto p = __builtin_amdgcn_cvt_pkrtz(a, b);   // __fp16 ext_vector(2)
    return __builtin_bit_cast(unsigned int, p);
}

// f32 sigmoid-form GELU with log2e folded into the polynomial:
//   gelu(x) ~= x * sigmoid(x*(c1 + c2*x^2)),  exp via exp2. 7 VALU ops.
__device__ __forceinline__ float gelu_sig(float x) {
    float t = fmaf(0.1029433247f, x * x, 2.3022089899f);  // log2e*(c1+c2*xx)
    float e = __builtin_amdgcn_exp2f(-x * t);
    return x * __builtin_amdgcn_rcpf(1.0f + e);
}

// packed f16 compare-exchange (descending): exact for our even-int values.
__device__ __forceinline__ void ce2(h2& x, h2& y) {
    h2 mx = __builtin_elementwise_max(x, y);
    h2 mn = __builtin_elementwise_min(x, y);
    x = mx; y = mn;
}

// DPP row_ror sum-reduce: rotations by 1,2,4,8 within the 16-lane row.
template<int CTRL>
__device__ __forceinline__ f32x4 dpp_add4(f32x4 x) {
#pragma unroll
    for (int r = 0; r < 4; ++r) {
        int o = __builtin_amdgcn_update_dpp(0, __float_as_int(x[r]),
                                            CTRL, 0xf, 0xf, false);
        x[r] += __int_as_float(o);
    }
    return x;
}
__device__ __forceinline__ f32x4 row_reduce16(f32x4 x) {
    x = dpp_add4<0x121>(x);   // row_ror:1
    x = dpp_add4<0x122>(x);   // row_ror:2
    x = dpp_add4<0x124>(x);   // row_ror:4
    x = dpp_add4<0x128>(x);   // row_ror:8
    return x;
}

// ---- setup kernel: fragment-ordered SINGLE-f16 (RTN) weights (r19 --
// absmax unchanged at 2^-6: act-f16 rounding dominates; halves MFMA count).
// Layout: half8 frag[L][nt][s][lane]  (3*4*2*64 half8 = 24KB).
// COLUMN-INTERLEAVED N: lane i owns col n = 4*i+nt. SCALE FOLD: W1 rows
// {0..7, 17..32} carry the 1/64 (exponent shift on the f32 BEFORE rounding).
__global__ void weight_stage_kernel(const float* __restrict__ W1,
                                    const float* __restrict__ W2,
                                    const float* __restrict__ W3,
                                    _Float16* __restrict__ wsW) {
    const int idx = blockIdx.x * 256 + threadIdx.x;  // 12288 (L,nt,s,lane,e)
    if (idx >= 3 * 4 * 2 * 64 * 8) return;
    const int e    = idx & 7;
    const int lane = (idx >> 3) & 63;
    const int s    = (idx >> 9) & 1;
    const int nt   = (idx >> 10) & 3;
    const int L    = idx >> 12;
    const int g = lane >> 4, i = lane & 15;
    const int k = 32 * s + 8 * g + e;     // K index this slot consumes
    const int n = 4 * i + nt;             // N index this lane owns (interleaved)
    const float* W = (L == 0) ? W1 : (L == 1) ? W2 : W3;
    const int K = (L == 0) ? 33 : 64;
    float val = (k < K) ? W[k * 64 + n] : 0.0f;  // W is [k][n]
    if (L == 0 && (k < 8 || (k >= 17 && k < 33))) val *= 0.015625f;
    const size_t base = (((size_t)L * 4 + nt) * 2 + s) * 512
                        + (size_t)lane * 8 + e;
    wsW[base] = (_Float16)val;            // RTN
}

// One MLP layer on a wave's 64x64 tile via mfma_f32_16x16x32_f16.
// Single-f16 weights (r19). LN via DPP fused mean+var. Params from GLOBAL
// float4 (L1-hot broadcast). A-fragment software pipeline (r14) + T5
// setprio around MFMA (r16) + B_pre preload (r17).
// ROUND 21: CHAIN B-PREFETCH -- issue next layer's 8 B-fragment loads at
// the top of this layer; their ~500cy latency hides under this layer's
// 8 MFMAs + epilogue, so the next layer starts hot (r19 freed 64 VGPRs;
// +32 live here stays well under the 128 cap).
template<bool LAST>
__device__ __forceinline__ void mfma_layer(
    _Float16* actB,                       // this wave's swizzled 64x64 tile
    const _Float16* __restrict__ wsL,     // frag[nt][s][lane] for layer
    const half8 (*B_pre)[2],              // preloaded frags or nullptr
    const _Float16* __restrict__ wsNext,  // next layer frags or nullptr
    half8 (*B_next)[2],                   // out: prefetched next-layer frags
    const float* __restrict__ bias, const float* __restrict__ gg,
    const float* __restrict__ bb,
    float* outp, int rowbase, int nrows)
{
    const int l = threadIdx.x & 63;
    const int g = l >> 4, i = l & 15;

    // B fragments: from prefetch regs (hot) or coalesced half8 loads.
    const half8* Bp = reinterpret_cast<const half8*>(wsL);
    half8 B[4][2];
#pragma unroll
    for (int nt = 0; nt < 4; ++nt) {
#pragma unroll
        for (int s = 0; s < 2; ++s) {
            B[nt][s] = B_pre ? B_pre[nt][s] : Bp[(nt * 2 + s) * 64 + l];
        }
    }
    // chain-prefetch next layer's B NOW: consumed after this whole layer.
    if (wsNext) {
        const half8* Bn = reinterpret_cast<const half8*>(wsNext);
#pragma unroll
        for (int nt = 0; nt < 4; ++nt)
#pragma unroll
            for (int s = 0; s < 2; ++s)
                B_next[nt][s] = Bn[(nt * 2 + s) * 64 + l];
    }
    // per-lane params: cols 4i..4i+3 -> single float4 GLOBAL loads (L1-hot)
    const f32x4 bvv = *(const f32x4*)&bias[4 * i];
    f32x4 gvv, bevv;
    if (!LAST) {
        gvv  = *(const f32x4*)&gg[4 * i];
        bevv = *(const f32x4*)&bb[4 * i];
    }
    const bool full = LAST && (rowbase + 63 < nrows);

    // prologue: t=0 A-fragments
    half8 A0 = *(const half8*)&actB[swz(i, 8 * g)];
    half8 A1 = *(const half8*)&actB[swz(i, 32 + 8 * g)];

#pragma unroll
    for (int t = 0; t < 4; ++t) {
        // prefetch t+1's A-fragments (disjoint rows -> no hazard with the
        // epilogue writes below; latency hides under MFMA+LN+GELU of t).
        half8 nA0, nA1;
        if (t < 3) {
            nA0 = *(const half8*)&actB[swz(16 * (t + 1) + i, 8 * g)];
            nA1 = *(const half8*)&actB[swz(16 * (t + 1) + i, 32 + 8 * g)];
        }
        f32x4 D[4];
        __builtin_amdgcn_s_setprio(1);
#pragma unroll
        for (int nt = 0; nt < 4; ++nt) {
            f32x4 d = {bvv[nt], bvv[nt], bvv[nt], bvv[nt]};
            d = __builtin_amdgcn_mfma_f32_16x16x32_f16(A0, B[nt][0], d, 0, 0, 0);
            d = __builtin_amdgcn_mfma_f32_16x16x32_f16(A1, B[nt][1], d, 0, 0, 0);
            D[nt] = d;
        }
        __builtin_amdgcn_s_setprio(0);
        if (LAST) {
            // row = 16t+4g+r, this lane's cols = [4i, 4i+4) -> float4 store
#pragma unroll
            for (int r = 0; r < 4; ++r) {
                const int grow = rowbase + 16 * t + 4 * g + r;
                if (full || grow < nrows) {
                    f32x4 st = {D[0][r], D[1][r], D[2][r], D[3][r]};
                    *reinterpret_cast<f32x4*>(&outp[(size_t)grow * 64 + 4 * i]) = st;
                }
            }
        } else {
            // fused mean+var across the 16-lane group in one DPP pass.
            f32x4 s4 = (D[0] + D[1]) + (D[2] + D[3]);
            f32x4 q4 = D[0] * D[0];
            q4 = D[1] * D[1] + q4;
            q4 = D[2] * D[2] + q4;
            q4 = D[3] * D[3] + q4;
            s4 = row_reduce16(s4);
            q4 = row_reduce16(q4);
            f32x4 mean = s4 * 0.015625f;
            f32x4 rstd, mr;
#pragma unroll
            for (int r = 0; r < 4; ++r) {
                float var = q4[r] * 0.015625f - mean[r] * mean[r];
                rstd[r] = rsqrtf(var + 1e-5f);
                mr[r] = -mean[r] * rstd[r];       // normalize as ONE fma
            }
            // normalize (2 fma) -> GELU -> pack f16 -> b64 write
#pragma unroll
            for (int r = 0; r < 4; ++r) {
                float x0 = fmaf(fmaf(D[0][r], rstd[r], mr[r]), gvv[0], bevv[0]);
                float x1 = fmaf(fmaf(D[1][r], rstd[r], mr[r]), gvv[1], bevv[1]);
                float x2 = fmaf(fmaf(D[2][r], rstd[r], mr[r]), gvv[2], bevv[2]);
                float x3 = fmaf(fmaf(D[3][r], rstd[r], mr[r]), gvv[3], bevv[3]);
                uint2 st;
                st.x = pk_f16(gelu_sig(x0), gelu_sig(x1));
                st.y = pk_f16(gelu_sig(x2), gelu_sig(x3));
                *reinterpret_cast<uint2*>(
                    &actB[swz(16 * t + 4 * g + r, 4 * i)]) = st;
            }
        }
        if (t < 3) { A0 = nA0; A1 = nA1; }
    }
    if (!LAST) asm volatile("s_waitcnt lgkmcnt(0)" ::: "memory");
}

// 1-wave blocks (r19, best measured: 81.97us), LDS = one 8192B act tile.
// r18/r20 finding: residency pins ~34% occupancy regardless of config
// arithmetic (TLP-insensitive past ~16 waves/CU). No __syncthreads.
__global__ __launch_bounds__(TPB, 2) void walsh_mlp_kernel(
    const int* __restrict__ tt,
    const float* __restrict__ b1,
    const float* __restrict__ g1, const float* __restrict__ be1,
    const float* __restrict__ b2,
    const float* __restrict__ g2, const float* __restrict__ be2,
    const float* __restrict__ b3,
    const _Float16* __restrict__ wsW,
    float* __restrict__ out, int nrows)
{
    __shared__ __align__(16) _Float16 sAct[64][64];   // 8192B EXACTLY

    const int tid = threadIdx.x;
    const int l = tid & 63;
    _Float16* actB = &sAct[0][0];

    const int row = blockIdx.x * TPB + tid;
    const int rowc = (row < nrows) ? row : (nrows - 1);  // clamp; no early exit

    // ---- HOISTED input loads: issue the 16 b128 loads first so the HBM
    // latency hides under the LUT build + FWHT front.
    int4 raw[16];
    const int4* t4 = reinterpret_cast<const int4*>(tt + (size_t)rowc * 64);
#pragma unroll
    for (int q = 0; q < 16; ++q) raw[q] = t4[q];

    // ---- per-wave entropy LUT in the wave's OWN tile (first 132B).
    // Lockstep-safe (r15/r18-verified): every lane's stats reads are
    // program-order before the assemble writes that overwrite this region.
    {
        float* lut = reinterpret_cast<float*>(actB);
        if (l < 33) {
            const float a = 2.0f * (float)l;
            const float pq = (a * a) * 2.44140625e-4f;   // /4096 exact
            lut[l] = -(pq * __logf(pq + 1e-10f));
        }
    }
    asm volatile("s_waitcnt lgkmcnt(0)" ::: "memory");

    // ---- build PACKED polar f16 p[i] = (x[i], x[i+32]) via bit-trick:
    // f16(1-2t) = 0x3C00 | (t<<15) for t in {0,1}. Exact.
    h2 p[32];
#pragma unroll
    for (int q = 0; q < 8; ++q) {
        int4 alo = raw[q];        // x[4q .. 4q+3]
        int4 ahi = raw[q + 8];    // x[32+4q .. 32+4q+3]
        p[4 * q + 0] = __builtin_bit_cast(h2,
            0x3C003C00u | ((unsigned)alo.x << 15) | ((unsigned)ahi.x << 31));
        p[4 * q + 1] = __builtin_bit_cast(h2,
            0x3C003C00u | ((unsigned)alo.y << 15) | ((unsigned)ahi.y << 31));
        p[4 * q + 2] = __builtin_bit_cast(h2,
            0x3C003C00u | ((unsigned)alo.z << 15) | ((unsigned)ahi.z << 31));
        p[4 * q + 3] = __builtin_bit_cast(h2,
            0x3C003C00u | ((unsigned)alo.w << 15) | ((unsigned)ahi.w << 31));
    }

    // ---- packed FWHT stages h=1..16: pairing (i,i+32) keeps both butterflies
    // of each pack in lockstep. Intermediates are ints <=32 -> f16-exact.
#pragma unroll
    for (int h = 1; h < 32; h <<= 1) {
#pragma unroll
        for (int i = 0; i < 32; ++i) {
            if ((i & h) == 0) {
                h2 a = p[i], b = p[i | h];
                p[i] = a + b;
                p[i | h] = a - b;
            }
        }
    }

    // ---- fused final stage (h=32) + key coeffs (RAW walsh -- 1/64 folded
    // into W1 rows at staging) + abs-packs + PACKED stats.
    const float inv_n = 1.0f / 64.0f;
    const float* lutr = reinterpret_cast<const float*>(actB);
    float f[17];
    h2 habs[32];
    const h2 kONE  = {(_Float16)1.0f, (_Float16)1.0f};
    const h2 kZERO = {(_Float16)0.0f, (_Float16)0.0f};
    const h2 k64   = {(_Float16)64.0f, (_Float16)64.0f};
    const h2 kCsp  = {(_Float16)409.5f, (_Float16)409.5f};
    const h2 kClg  = {(_Float16)-2080.0f, (_Float16)-2080.0f};
    const h2 kM8   = {(_Float16)-8.0f, (_Float16)-8.0f};
    h2 sum2 = kZERO, max2 = kZERO, bent2 = kZERO;
    h2 csp2 = kZERO, clg2 = kZERO, chw2 = kZERO;
    float ent = 0.0f;
#pragma unroll
    for (int i = 0; i < 32; ++i) {
        const float lo = (float)p[i][0], hi = (float)p[i][1];
        const float a0 = lo + hi;        // v[i]
        const float a1 = lo - hi;        // v[i+32]
        if (i == 0)  { f[0] = a0; f[6] = a1; }
        if (i == 1)  f[1] = a0;
        if (i == 2)  f[2] = a0;
        if (i == 4)  f[3] = a0;
        if (i == 8)  f[4] = a0;
        if (i == 16) f[5] = a0;
        if (i == 31) f[7] = a1;
        const h2 a = __builtin_bit_cast(h2, pk_f16(a0, a1) & 0x7FFF7FFFu);
        habs[i] = a;
        sum2 = sum2 + a;
        max2 = __builtin_elementwise_max(max2, a);
        bent2 = bent2 + __builtin_bit_cast(h2,
            __builtin_bit_cast(unsigned, a + kM8) & 0x7FFF7FFFu);   // |a-8|
        const h2 ssp = __builtin_elementwise_min(kONE,
            __builtin_elementwise_max(kZERO, kCsp - a * k64));       // a<6.4
        csp2 = csp2 + ssp;
        clg2 = clg2 + __builtin_elementwise_min(kONE,
            __builtin_elementwise_max(kZERO, a * k64 + kClg));       // a>32
        const float PC = (float)__builtin_popcount(i);               // const
        const h2 hp = {(_Float16)PC, (_Float16)PC};
        chw2 = chw2 + (kONE - ssp) * hp;   // popc(i+32)=popc(i)+1 fixed below
        ent += lutr[((int)fabsf(a0)) >> 1];
        ent += lutr[((int)fabsf(a1)) >> 1];
    }
    const float sumabs = (float)sum2[0] + (float)sum2[1];
    const float maxab  = fmaxf((float)max2[0], (float)max2[1]);
    const float bent   = (float)bent2[0] + (float)bent2[1];
    const float cnt_sp = (float)csp2[0] + (float)csp2[1];
    const float cnt_lg = (float)clg2[0] + (float)clg2[1];
    // hi-half popc correction: sum over hi of (popc+1)*step = chw.hi + (32-csp.hi)
    const float sum_hw = (float)chw2[0] + (float)chw2[1]
                       + (32.0f - (float)csp2[1]);

    f[8]  = cnt_sp * inv_n;
    f[9]  = maxab * inv_n;
    f[10] = sumabs * (1.0f / 4096.0f);
    f[11] = 0.015625f;  // l2 == 1/64 always (Parseval)
    f[12] = ent * 0.24044917348149316f;
    f[13] = (cnt_lg >= 0.5f && cnt_lg <= 2.5f) ? 1.0f : 0.0f;
    f[14] = fmaxf(0.0f, 0.5f - maxab * (1.0f / 128.0f)) * 2.0f;
    f[15] = sum_hw / (64.0f - cnt_sp + 1e-10f) * (1.0f / 6.0f);
    f[16] = (bent < 51.2f) ? 1.0f : 0.0f;

    // ---- top-16 in PACKED f16 on habs ((i,i+32) pairing, verified).
    // The two Batcher-16 sorts are independent -> interleaved body (r17,
    // 2x ILP on phase-1's longest chain). Same comparators -> bit-identical.
    h2 t2[16];
    {
#pragma unroll
        for (int pp = 1; pp < 16; pp <<= 1) {
#pragma unroll
            for (int k = pp; k >= 1; k >>= 1) {
#pragma unroll
                for (int j = k & (pp - 1); j + k < 16; j += 2 * k) {
#pragma unroll
                    for (int i = 0; i < k; ++i) {
                        if (i + j + k < 16 &&
                            (i + j) / (2 * pp) == (i + j + k) / (2 * pp)) {
                            ce2(habs[i + j],      habs[i + j + k]);
                            ce2(habs[16 + i + j], habs[16 + i + j + k]);
                        }
                    }
                }
            }
        }
        h2 mm[16];
#pragma unroll
        for (int i = 0; i < 16; ++i)
            mm[i] = __builtin_elementwise_max(habs[i], habs[31 - i]);
#pragma unroll
        for (int d = 8; d >= 1; d >>= 1) {
#pragma unroll
            for (int i = 0; i < 16; ++i)
                if ((i & d) == 0) ce2(mm[i], mm[i + d]);
        }
#pragma unroll
        for (int i = 0; i < 16; ++i) {
            unsigned m = __builtin_bit_cast(unsigned, mm[15 - i]);
            unsigned sw = __builtin_amdgcn_alignbit(m, m, 16);  // halves swapped
            t2[i] = __builtin_elementwise_max(mm[i], __builtin_bit_cast(h2, sw));
        }
#pragma unroll
        for (int d = 8; d >= 1; d >>= 1) {
#pragma unroll
            for (int i = 0; i < 16; ++i)
                if ((i & d) == 0) ce2(t2[i], t2[i + d]);
        }
    }

    // ================= MLP via MFMA =================
    // preload layer-1's B-fragments (r17): latency hides under assemble.
    half8 B1[4][2];
    {
        const half8* Bp1 = reinterpret_cast<const half8*>(wsW);
#pragma unroll
        for (int nt = 0; nt < 4; ++nt)
#pragma unroll
            for (int s = 0; s < 2; ++s)
                B1[nt][s] = Bp1[(nt * 2 + s) * 64 + l];
    }

    // assemble act row l: halves 0..16 = f[0..16], 17..32 = top16, rest 0
    // (overwrites the per-wave LUT region -- all lanes' LUT reads are done,
    // guaranteed by wave lockstep + program order)
    {
        unsigned wd[32];
#pragma unroll
        for (int j = 0; j < 8; ++j) wd[j] = pk_f16(f[2 * j], f[2 * j + 1]);
        {
            unsigned lo = (unsigned)__builtin_bit_cast(unsigned short,
                                                       (_Float16)f[16]);
            wd[8] = lo | (__builtin_bit_cast(unsigned, t2[0]) << 16);
        }
#pragma unroll
        for (int m = 0; m < 7; ++m)
            wd[9 + m] = (__builtin_bit_cast(unsigned, t2[2 * m + 1]) & 0xFFFFu)
                      | (__builtin_bit_cast(unsigned, t2[2 * m + 2]) << 16);
        wd[16] = __builtin_bit_cast(unsigned, t2[15]) & 0xFFFFu;
#pragma unroll
        for (int j = 17; j < 32; ++j) wd[j] = 0u;
#pragma unroll
        for (int c = 0; c < 8; ++c) {
            uint4 st;
            st.x = wd[4 * c + 0]; st.y = wd[4 * c + 1];
            st.z = wd[4 * c + 2]; st.w = wd[4 * c + 3];
            *reinterpret_cast<uint4*>(&actB[swz(l, c * 8)]) = st;
        }
    }
    asm volatile("s_waitcnt lgkmcnt(0)" ::: "memory");

    const int rowbase = blockIdx.x * TPB;
    half8 B2[4][2], B3[4][2];
    mfma_layer<false>(actB, wsW,         B1,      wsW + 4096, B2,
                      b1, g1, be1, nullptr, 0, 0);
    mfma_layer<false>(actB, wsW + 4096,  B2,      wsW + 8192, B3,
                      b2, g2, be2, nullptr, 0, 0);
    mfma_layer<true >(actB, wsW + 8192,  B3,      nullptr,    nullptr,
                      b3, nullptr, nullptr, out, rowbase, nrows);
}

extern "C" void kernel_launch(void* const* d_in, const int* in_sizes, int n_in,
                              void* d_out, int out_size, void* d_ws, size_t ws_size,
                              hipStream_t stream) {
    const int*   tt  = (const int*)d_in[0];
    // d_in[1] is the Hadamard matrix H -- unused (in-register FWHT)
    const float* W1  = (const float*)d_in[2];
    const float* b1  = (const float*)d_in[3];
    const float* g1  = (const float*)d_in[4];
    const float* be1 = (const float*)d_in[5];
    const float* W2  = (const float*)d_in[6];
    const float* b2  = (const float*)d_in[7];
    const float* g2  = (const float*)d_in[8];
    const float* be2 = (const float*)d_in[9];
    const float* W3  = (const float*)d_in[10];
    const float* b3  = (const float*)d_in[11];
    float* out = (float*)d_out;
    _Float16* wsW = (_Float16*)d_ws;   // 24KB fragment-ordered RTN-f16 weights

    const int nrows = in_sizes[0] / 64;

    // stage weights into fragment order (tiny; runs in-stream each call)
    hipLaunchKernelGGL(weight_stage_kernel, dim3(48), dim3(256), 0, stream,
                       W1, W2, W3, wsW);

    const int grid = (nrows + TPB - 1) / TPB;
    hipLaunchKernelGGL(walsh_mlp_kernel, dim3(grid), dim3(TPB), 0, stream,
                       tt, b1, g1, be1, b2, g2, be2, b3, wsW, out, nrows);
}

// Round 22
// 81.879 us; speedup vs baseline: 1.0244x; 1.0244x over previous
//
#include <hip/hip_runtime.h>
#include <math.h>

#define TPB 64

typedef _Float16 half8 __attribute__((ext_vector_type(8)));
typedef _Float16 h2 __attribute__((ext_vector_type(2)));
typedef float f32x4 __attribute__((ext_vector_type(4)));

// ---- XOR swizzle for the [64][64] f16 act tile (row = 128B = 32 banks).
// Verified: SQ_LDS_BANK_CONFLICT 1.285e7 -> 0 (round 4).
__device__ __forceinline__ int swz(int row, int col) {
    return row * 64 + ((((col >> 3) ^ row) & 7) << 3) + (col & 7);
}

// pack two f32 -> one u32 of 2 f16 (RTZ; exact for the small ints we pack).
__device__ __forceinline__ unsigned int pk_f16(float a, float b) {
    auto p = __builtin_amdgcn_cvt_pkrtz(a, b);   // __fp16 ext_vector(2)
    return __builtin_bit_cast(unsigned int, p);
}

// f32 sigmoid-form GELU with log2e folded into the polynomial:
//   gelu(x) ~= x * sigmoid(x*(c1 + c2*x^2)),  exp via exp2. 7 VALU ops.
__device__ __forceinline__ float gelu_sig(float x) {
    float t = fmaf(0.1029433247f, x * x, 2.3022089899f);  // log2e*(c1+c2*xx)
    float e = __builtin_amdgcn_exp2f(-x * t);
    return x * __builtin_amdgcn_rcpf(1.0f + e);
}

// packed f16 compare-exchange (descending): exact for our even-int values.
__device__ __forceinline__ void ce2(h2& x, h2& y) {
    h2 mx = __builtin_elementwise_max(x, y);
    h2 mn = __builtin_elementwise_min(x, y);
    x = mx; y = mn;
}

// DPP row_ror sum-reduce: rotations by 1,2,4,8 within the 16-lane row.
template<int CTRL>
__device__ __forceinline__ f32x4 dpp_add4(f32x4 x) {
#pragma unroll
    for (int r = 0; r < 4; ++r) {
        int o = __builtin_amdgcn_update_dpp(0, __float_as_int(x[r]),
                                            CTRL, 0xf, 0xf, false);
        x[r] += __int_as_float(o);
    }
    return x;
}
__device__ __forceinline__ f32x4 row_reduce16(f32x4 x) {
    x = dpp_add4<0x121>(x);   // row_ror:1
    x = dpp_add4<0x122>(x);   // row_ror:2
    x = dpp_add4<0x124>(x);   // row_ror:4
    x = dpp_add4<0x128>(x);   // row_ror:8
    return x;
}

// ---- setup kernel: fragment-ordered SINGLE-f16 (RTN) weights (r19 --
// absmax unchanged at 2^-6: act-f16 rounding dominates; halves MFMA count).
// Layout: half8 frag[L][nt][s][lane]  (3*4*2*64 half8 = 24KB).
// COLUMN-INTERLEAVED N: lane i owns col n = 4*i+nt. SCALE FOLD: W1 rows
// {0..7, 17..32} carry the 1/64 (exponent shift on the f32 BEFORE rounding).
__global__ void weight_stage_kernel(const float* __restrict__ W1,
                                    const float* __restrict__ W2,
                                    const float* __restrict__ W3,
                                    _Float16* __restrict__ wsW) {
    const int idx = blockIdx.x * 256 + threadIdx.x;  // 12288 (L,nt,s,lane,e)
    if (idx >= 3 * 4 * 2 * 64 * 8) return;
    const int e    = idx & 7;
    const int lane = (idx >> 3) & 63;
    const int s    = (idx >> 9) & 1;
    const int nt   = (idx >> 10) & 3;
    const int L    = idx >> 12;
    const int g = lane >> 4, i = lane & 15;
    const int k = 32 * s + 8 * g + e;     // K index this slot consumes
    const int n = 4 * i + nt;             // N index this lane owns (interleaved)
    const float* W = (L == 0) ? W1 : (L == 1) ? W2 : W3;
    const int K = (L == 0) ? 33 : 64;
    float val = (k < K) ? W[k * 64 + n] : 0.0f;  // W is [k][n]
    if (L == 0 && (k < 8 || (k >= 17 && k < 33))) val *= 0.015625f;
    const size_t base = (((size_t)L * 4 + nt) * 2 + s) * 512
                        + (size_t)lane * 8 + e;
    wsW[base] = (_Float16)val;            // RTN
}

// One MLP layer on a wave's 64x64 tile via mfma_f32_16x16x32_f16.
// Single-f16 weights (r19). LN via DPP fused mean+var. Params from GLOBAL
// float4 (L1-hot broadcast). A-fragment software pipeline (r14) + T5
// setprio around MFMA (r16) + B_pre preload for layer 1 (r17).
// r21 lesson: chain-prefetching later layers' B costs +16 VGPR -> occupancy
// drop -> net NEGATIVE. VGPR count is the occupancy lever at this point.
template<bool LAST>
__device__ __forceinline__ void mfma_layer(
    _Float16* actB,                       // this wave's swizzled 64x64 tile
    const _Float16* __restrict__ wsL,     // frag[nt][s][lane] for layer
    const half8 (*B_pre)[2],              // preloaded frags or nullptr
    const float* __restrict__ bias, const float* __restrict__ gg,
    const float* __restrict__ bb,
    float* outp, int rowbase, int nrows)
{
    const int l = threadIdx.x & 63;
    const int g = l >> 4, i = l & 15;

    // B fragments: coalesced half8 loads, reused across all 4 M-tiles.
    const half8* Bp = reinterpret_cast<const half8*>(wsL);
    half8 B[4][2];
#pragma unroll
    for (int nt = 0; nt < 4; ++nt) {
#pragma unroll
        for (int s = 0; s < 2; ++s) {
            B[nt][s] = B_pre ? B_pre[nt][s] : Bp[(nt * 2 + s) * 64 + l];
        }
    }
    // per-lane params: cols 4i..4i+3 -> single float4 GLOBAL loads (L1-hot)
    const f32x4 bvv = *(const f32x4*)&bias[4 * i];
    f32x4 gvv, bevv;
    if (!LAST) {
        gvv  = *(const f32x4*)&gg[4 * i];
        bevv = *(const f32x4*)&bb[4 * i];
    }
    const bool full = LAST && (rowbase + 63 < nrows);

    // prologue: t=0 A-fragments
    half8 A0 = *(const half8*)&actB[swz(i, 8 * g)];
    half8 A1 = *(const half8*)&actB[swz(i, 32 + 8 * g)];

#pragma unroll
    for (int t = 0; t < 4; ++t) {
        // prefetch t+1's A-fragments (disjoint rows -> no hazard with the
        // epilogue writes below; latency hides under MFMA+LN+GELU of t).
        half8 nA0, nA1;
        if (t < 3) {
            nA0 = *(const half8*)&actB[swz(16 * (t + 1) + i, 8 * g)];
            nA1 = *(const half8*)&actB[swz(16 * (t + 1) + i, 32 + 8 * g)];
        }
        f32x4 D[4];
        __builtin_amdgcn_s_setprio(1);
#pragma unroll
        for (int nt = 0; nt < 4; ++nt) {
            f32x4 d = {bvv[nt], bvv[nt], bvv[nt], bvv[nt]};
            d = __builtin_amdgcn_mfma_f32_16x16x32_f16(A0, B[nt][0], d, 0, 0, 0);
            d = __builtin_amdgcn_mfma_f32_16x16x32_f16(A1, B[nt][1], d, 0, 0, 0);
            D[nt] = d;
        }
        __builtin_amdgcn_s_setprio(0);
        if (LAST) {
            // row = 16t+4g+r, this lane's cols = [4i, 4i+4) -> float4 store
#pragma unroll
            for (int r = 0; r < 4; ++r) {
                const int grow = rowbase + 16 * t + 4 * g + r;
                if (full || grow < nrows) {
                    f32x4 st = {D[0][r], D[1][r], D[2][r], D[3][r]};
                    *reinterpret_cast<f32x4*>(&outp[(size_t)grow * 64 + 4 * i]) = st;
                }
            }
        } else {
            // fused mean+var across the 16-lane group in one DPP pass.
            f32x4 s4 = (D[0] + D[1]) + (D[2] + D[3]);
            f32x4 q4 = D[0] * D[0];
            q4 = D[1] * D[1] + q4;
            q4 = D[2] * D[2] + q4;
            q4 = D[3] * D[3] + q4;
            s4 = row_reduce16(s4);
            q4 = row_reduce16(q4);
            f32x4 mean = s4 * 0.015625f;
            f32x4 rstd, mr;
#pragma unroll
            for (int r = 0; r < 4; ++r) {
                float var = q4[r] * 0.015625f - mean[r] * mean[r];
                rstd[r] = rsqrtf(var + 1e-5f);
                mr[r] = -mean[r] * rstd[r];       // normalize as ONE fma
            }
            // normalize (2 fma) -> GELU -> pack f16 -> b64 write
#pragma unroll
            for (int r = 0; r < 4; ++r) {
                float x0 = fmaf(fmaf(D[0][r], rstd[r], mr[r]), gvv[0], bevv[0]);
                float x1 = fmaf(fmaf(D[1][r], rstd[r], mr[r]), gvv[1], bevv[1]);
                float x2 = fmaf(fmaf(D[2][r], rstd[r], mr[r]), gvv[2], bevv[2]);
                float x3 = fmaf(fmaf(D[3][r], rstd[r], mr[r]), gvv[3], bevv[3]);
                uint2 st;
                st.x = pk_f16(gelu_sig(x0), gelu_sig(x1));
                st.y = pk_f16(gelu_sig(x2), gelu_sig(x3));
                *reinterpret_cast<uint2*>(
                    &actB[swz(16 * t + 4 * g + r, 4 * i)]) = st;
            }
        }
        if (t < 3) { A0 = nA0; A1 = nA1; }
    }
    if (!LAST) asm volatile("s_waitcnt lgkmcnt(0)" ::: "memory");
}

// FINAL (r19 configuration, measured best 81.97us): 1-wave blocks, LDS =
// one 8192B act tile, VGPR 64. Session findings: instruction cuts absorbed
// (r13), scheduling ~+-1% (r14/r16/r17), TLP pinned ~11 waves/CU across all
// configs (r15/r18/r20), register-costly prefetch negative (r21).
// No __syncthreads anywhere.
__global__ __launch_bounds__(TPB, 2) void walsh_mlp_kernel(
    const int* __restrict__ tt,
    const float* __restrict__ b1,
    const float* __restrict__ g1, const float* __restrict__ be1,
    const float* __restrict__ b2,
    const float* __restrict__ g2, const float* __restrict__ be2,
    const float* __restrict__ b3,
    const _Float16* __restrict__ wsW,
    float* __restrict__ out, int nrows)
{
    __shared__ __align__(16) _Float16 sAct[64][64];   // 8192B EXACTLY

    const int tid = threadIdx.x;
    const int l = tid & 63;
    _Float16* actB = &sAct[0][0];

    const int row = blockIdx.x * TPB + tid;
    const int rowc = (row < nrows) ? row : (nrows - 1);  // clamp; no early exit

    // ---- HOISTED input loads: issue the 16 b128 loads first so the HBM
    // latency hides under the LUT build + FWHT front.
    int4 raw[16];
    const int4* t4 = reinterpret_cast<const int4*>(tt + (size_t)rowc * 64);
#pragma unroll
    for (int q = 0; q < 16; ++q) raw[q] = t4[q];

    // ---- per-wave entropy LUT in the wave's OWN tile (first 132B).
    // Lockstep-safe (r15/r18-verified): every lane's stats reads are
    // program-order before the assemble writes that overwrite this region.
    {
        float* lut = reinterpret_cast<float*>(actB);
        if (l < 33) {
            const float a = 2.0f * (float)l;
            const float pq = (a * a) * 2.44140625e-4f;   // /4096 exact
            lut[l] = -(pq * __logf(pq + 1e-10f));
        }
    }
    asm volatile("s_waitcnt lgkmcnt(0)" ::: "memory");

    // ---- build PACKED polar f16 p[i] = (x[i], x[i+32]) via bit-trick:
    // f16(1-2t) = 0x3C00 | (t<<15) for t in {0,1}. Exact.
    h2 p[32];
#pragma unroll
    for (int q = 0; q < 8; ++q) {
        int4 alo = raw[q];        // x[4q .. 4q+3]
        int4 ahi = raw[q + 8];    // x[32+4q .. 32+4q+3]
        p[4 * q + 0] = __builtin_bit_cast(h2,
            0x3C003C00u | ((unsigned)alo.x << 15) | ((unsigned)ahi.x << 31));
        p[4 * q + 1] = __builtin_bit_cast(h2,
            0x3C003C00u | ((unsigned)alo.y << 15) | ((unsigned)ahi.y << 31));
        p[4 * q + 2] = __builtin_bit_cast(h2,
            0x3C003C00u | ((unsigned)alo.z << 15) | ((unsigned)ahi.z << 31));
        p[4 * q + 3] = __builtin_bit_cast(h2,
            0x3C003C00u | ((unsigned)alo.w << 15) | ((unsigned)ahi.w << 31));
    }

    // ---- packed FWHT stages h=1..16: pairing (i,i+32) keeps both butterflies
    // of each pack in lockstep. Intermediates are ints <=32 -> f16-exact.
#pragma unroll
    for (int h = 1; h < 32; h <<= 1) {
#pragma unroll
        for (int i = 0; i < 32; ++i) {
            if ((i & h) == 0) {
                h2 a = p[i], b = p[i | h];
                p[i] = a + b;
                p[i | h] = a - b;
            }
        }
    }

    // ---- fused final stage (h=32) + key coeffs (RAW walsh -- 1/64 folded
    // into W1 rows at staging) + abs-packs + PACKED stats.
    const float inv_n = 1.0f / 64.0f;
    const float* lutr = reinterpret_cast<const float*>(actB);
    float f[17];
    h2 habs[32];
    const h2 kONE  = {(_Float16)1.0f, (_Float16)1.0f};
    const h2 kZERO = {(_Float16)0.0f, (_Float16)0.0f};
    const h2 k64   = {(_Float16)64.0f, (_Float16)64.0f};
    const h2 kCsp  = {(_Float16)409.5f, (_Float16)409.5f};
    const h2 kClg  = {(_Float16)-2080.0f, (_Float16)-2080.0f};
    const h2 kM8   = {(_Float16)-8.0f, (_Float16)-8.0f};
    h2 sum2 = kZERO, max2 = kZERO, bent2 = kZERO;
    h2 csp2 = kZERO, clg2 = kZERO, chw2 = kZERO;
    float ent = 0.0f;
#pragma unroll
    for (int i = 0; i < 32; ++i) {
        const float lo = (float)p[i][0], hi = (float)p[i][1];
        const float a0 = lo + hi;        // v[i]
        const float a1 = lo - hi;        // v[i+32]
        if (i == 0)  { f[0] = a0; f[6] = a1; }
        if (i == 1)  f[1] = a0;
        if (i == 2)  f[2] = a0;
        if (i == 4)  f[3] = a0;
        if (i == 8)  f[4] = a0;
        if (i == 16) f[5] = a0;
        if (i == 31) f[7] = a1;
        const h2 a = __builtin_bit_cast(h2, pk_f16(a0, a1) & 0x7FFF7FFFu);
        habs[i] = a;
        sum2 = sum2 + a;
        max2 = __builtin_elementwise_max(max2, a);
        bent2 = bent2 + __builtin_bit_cast(h2,
            __builtin_bit_cast(unsigned, a + kM8) & 0x7FFF7FFFu);   // |a-8|
        const h2 ssp = __builtin_elementwise_min(kONE,
            __builtin_elementwise_max(kZERO, kCsp - a * k64));       // a<6.4
        csp2 = csp2 + ssp;
        clg2 = clg2 + __builtin_elementwise_min(kONE,
            __builtin_elementwise_max(kZERO, a * k64 + kClg));       // a>32
        const float PC = (float)__builtin_popcount(i);               // const
        const h2 hp = {(_Float16)PC, (_Float16)PC};
        chw2 = chw2 + (kONE - ssp) * hp;   // popc(i+32)=popc(i)+1 fixed below
        ent += lutr[((int)fabsf(a0)) >> 1];
        ent += lutr[((int)fabsf(a1)) >> 1];
    }
    const float sumabs = (float)sum2[0] + (float)sum2[1];
    const float maxab  = fmaxf((float)max2[0], (float)max2[1]);
    const float bent   = (float)bent2[0] + (float)bent2[1];
    const float cnt_sp = (float)csp2[0] + (float)csp2[1];
    const float cnt_lg = (float)clg2[0] + (float)clg2[1];
    // hi-half popc correction: sum over hi of (popc+1)*step = chw.hi + (32-csp.hi)
    const float sum_hw = (float)chw2[0] + (float)chw2[1]
                       + (32.0f - (float)csp2[1]);

    f[8]  = cnt_sp * inv_n;
    f[9]  = maxab * inv_n;
    f[10] = sumabs * (1.0f / 4096.0f);
    f[11] = 0.015625f;  // l2 == 1/64 always (Parseval)
    f[12] = ent * 0.24044917348149316f;
    f[13] = (cnt_lg >= 0.5f && cnt_lg <= 2.5f) ? 1.0f : 0.0f;
    f[14] = fmaxf(0.0f, 0.5f - maxab * (1.0f / 128.0f)) * 2.0f;
    f[15] = sum_hw / (64.0f - cnt_sp + 1e-10f) * (1.0f / 6.0f);
    f[16] = (bent < 51.2f) ? 1.0f : 0.0f;

    // ---- top-16 in PACKED f16 on habs ((i,i+32) pairing, verified).
    // The two Batcher-16 sorts are independent -> interleaved body (r17,
    // 2x ILP on phase-1's longest chain). Same comparators -> bit-identical.
    h2 t2[16];
    {
#pragma unroll
        for (int pp = 1; pp < 16; pp <<= 1) {
#pragma unroll
            for (int k = pp; k >= 1; k >>= 1) {
#pragma unroll
                for (int j = k & (pp - 1); j + k < 16; j += 2 * k) {
#pragma unroll
                    for (int i = 0; i < k; ++i) {
                        if (i + j + k < 16 &&
                            (i + j) / (2 * pp) == (i + j + k) / (2 * pp)) {
                            ce2(habs[i + j],      habs[i + j + k]);
                            ce2(habs[16 + i + j], habs[16 + i + j + k]);
                        }
                    }
                }
            }
        }
        h2 mm[16];
#pragma unroll
        for (int i = 0; i < 16; ++i)
            mm[i] = __builtin_elementwise_max(habs[i], habs[31 - i]);
#pragma unroll
        for (int d = 8; d >= 1; d >>= 1) {
#pragma unroll
            for (int i = 0; i < 16; ++i)
                if ((i & d) == 0) ce2(mm[i], mm[i + d]);
        }
#pragma unroll
        for (int i = 0; i < 16; ++i) {
            unsigned m = __builtin_bit_cast(unsigned, mm[15 - i]);
            unsigned sw = __builtin_amdgcn_alignbit(m, m, 16);  // halves swapped
            t2[i] = __builtin_elementwise_max(mm[i], __builtin_bit_cast(h2, sw));
        }
#pragma unroll
        for (int d = 8; d >= 1; d >>= 1) {
#pragma unroll
            for (int i = 0; i < 16; ++i)
                if ((i & d) == 0) ce2(t2[i], t2[i + d]);
        }
    }

    // ================= MLP via MFMA =================
    // preload layer-1's B-fragments (r17): latency hides under assemble.
    half8 B1[4][2];
    {
        const half8* Bp1 = reinterpret_cast<const half8*>(wsW);
#pragma unroll
        for (int nt = 0; nt < 4; ++nt)
#pragma unroll
            for (int s = 0; s < 2; ++s)
                B1[nt][s] = Bp1[(nt * 2 + s) * 64 + l];
    }

    // assemble act row l: halves 0..16 = f[0..16], 17..32 = top16, rest 0
    // (overwrites the per-wave LUT region -- all lanes' LUT reads are done,
    // guaranteed by wave lockstep + program order)
    {
        unsigned wd[32];
#pragma unroll
        for (int j = 0; j < 8; ++j) wd[j] = pk_f16(f[2 * j], f[2 * j + 1]);
        {
            unsigned lo = (unsigned)__builtin_bit_cast(unsigned short,
                                                       (_Float16)f[16]);
            wd[8] = lo | (__builtin_bit_cast(unsigned, t2[0]) << 16);
        }
#pragma unroll
        for (int m = 0; m < 7; ++m)
            wd[9 + m] = (__builtin_bit_cast(unsigned, t2[2 * m + 1]) & 0xFFFFu)
                      | (__builtin_bit_cast(unsigned, t2[2 * m + 2]) << 16);
        wd[16] = __builtin_bit_cast(unsigned, t2[15]) & 0xFFFFu;
#pragma unroll
        for (int j = 17; j < 32; ++j) wd[j] = 0u;
#pragma unroll
        for (int c = 0; c < 8; ++c) {
            uint4 st;
            st.x = wd[4 * c + 0]; st.y = wd[4 * c + 1];
            st.z = wd[4 * c + 2]; st.w = wd[4 * c + 3];
            *reinterpret_cast<uint4*>(&actB[swz(l, c * 8)]) = st;
        }
    }
    asm volatile("s_waitcnt lgkmcnt(0)" ::: "memory");

    const int rowbase = blockIdx.x * TPB;
    mfma_layer<false>(actB, wsW,         B1,      b1, g1, be1,
                      nullptr, 0, 0);
    mfma_layer<false>(actB, wsW + 4096,  nullptr, b2, g2, be2,
                      nullptr, 0, 0);
    mfma_layer<true >(actB, wsW + 8192,  nullptr, b3, nullptr, nullptr,
                      out, rowbase, nrows);
}

extern "C" void kernel_launch(void* const* d_in, const int* in_sizes, int n_in,
                              void* d_out, int out_size, void* d_ws, size_t ws_size,
                              hipStream_t stream) {
    const int*   tt  = (const int*)d_in[0];
    // d_in[1] is the Hadamard matrix H -- unused (in-register FWHT)
    const float* W1  = (const float*)d_in[2];
    const float* b1  = (const float*)d_in[3];
    const float* g1  = (const float*)d_in[4];
    const float* be1 = (const float*)d_in[5];
    const float* W2  = (const float*)d_in[6];
    const float* b2  = (const float*)d_in[7];
    const float* g2  = (const float*)d_in[8];
    const float* be2 = (const float*)d_in[9];
    const float* W3  = (const float*)d_in[10];
    const float* b3  = (const float*)d_in[11];
    float* out = (float*)d_out;
    _Float16* wsW = (_Float16*)d_ws;   // 24KB fragment-ordered RTN-f16 weights

    const int nrows = in_sizes[0] / 64;

    // stage weights into fragment order (tiny; runs in-stream each call)
    hipLaunchKernelGGL(weight_stage_kernel, dim3(48), dim3(256), 0, stream,
                       W1, W2, W3, wsW);

    const int grid = (nrows + TPB - 1) / TPB;
    hipLaunchKernelGGL(walsh_mlp_kernel, dim3(grid), dim3(TPB), 0, stream,
                       tt, b1, g1, be1, b2, g2, be2, b3, wsW, out, nrows);
}